// Round 17
// baseline (205.062 us; speedup 1.0000x reference)
//
#include <hip/hip_runtime.h>
#include <math.h>

// B=32, C=12, H=64, W=64, hidden=128, cond_c=4, out_spline=276 (pad->288=12*24)
// NUM_BINS=8, TAIL=3.0, MBW=MBH=MD=0.001

#define NY   1572864

typedef _Float16 half8 __attribute__((ext_vector_type(8)));
typedef _Float16 half4 __attribute__((ext_vector_type(4)));
typedef float f32x4 __attribute__((ext_vector_type(4)));

// async global->LDS, 16B per lane: HW writes LDS base + lane*16; lds base wave-uniform
#define ASYNC16(gsrc, ldst) \
  __builtin_amdgcn_global_load_lds((const __attribute__((address_space(1))) unsigned int*)(gsrc), \
                                   (__attribute__((address_space(3))) unsigned int*)(ldst), 16, 0, 0)

// h2p layout: [b][cc=ci/32][pp=66*66][ci%32] fp16, halo ring of zeros
#define H2P_PLANE 4356            // 66*66
#define H2P_IDX(b, cc, pp) ((((size_t)(b) * 4 + (cc)) * H2P_PLANE + (pp)) << 5)
// xh layout: [b][pp=66*66][32] fp16 (ci<12 x, 12..15 cond, >=16 zero; halo zero)
#define XH_IDX(b, pp) (((size_t)(b) * H2P_PLANE + (pp)) << 5)

// ---------------------------------------------------------------------------
// prep + xh + halo-ring zero (merged):
//   w1 (128,16,3,3)  -> w1h[(t*128+oc)*32 + k]   k=ci<16 real, k>=16 zero   fp16
//   w2 (128,128,1,1) -> w2h[(ks*128+oc)*32 + km]  (ci=ks*32+km)             fp16
//   w3 (276,128,3,3) -> w3h[((t*4+cc)*288 + oc')*32 + cim]                  fp16
//                       oc' = c*24 + j (j<23 real, j=23 zero pad)
//   xh: pack x(12ch fp32) + cond(4ch fp32) into halo-padded fp16 [b][66*66][32]
// ---------------------------------------------------------------------------
__global__ __launch_bounds__(256) void prep_xh_k(
    const float* __restrict__ w1, const float* __restrict__ w2,
    const float* __restrict__ w3, _Float16* __restrict__ w1h,
    _Float16* __restrict__ w2h, _Float16* __restrict__ w3h,
    const float* __restrict__ logdet, float* __restrict__ ld_out,
    const float* __restrict__ x, const float* __restrict__ cond,
    _Float16* __restrict__ xh, _Float16* __restrict__ h2p)
{
    const int i = blockIdx.x * 256 + threadIdx.x;   // < 331776
    if (i < 36864) {                     // w1h
        int k = i & 31, oc = (i >> 5) & 127, t = i >> 12;
        w1h[i] = (_Float16)((k < 16) ? w1[(oc * 16 + k) * 9 + t] : 0.f);
    }
    if (i < 16384) {                     // w2h
        int km = i & 31, oc = (i >> 5) & 127, ks = i >> 12;
        w2h[i] = (_Float16)w2[oc * 128 + ks * 32 + km];
    }
    {   // w3h: flat i = ((t*4+cc)*288 + oc)*32 + cim
        int cim = i & 31;
        int oc = (i >> 5) % 288;
        int tc = i / (288 * 32);        // 0..35
        int t = tc >> 2, cc = tc & 3;
        int c = oc / 24, j = oc % 24;
        int ci = cc * 32 + cim;
        float v = (j < 23) ? w3[((c * 23 + j) * 128 + ci) * 9 + t] : 0.f;
        w3h[i] = (_Float16)v;
    }
    if (i < 32) ld_out[i] = logdet[i];

    if (i < 133120) {                    // h2p halo-ring zero
        const int q = i & 3;
        const int rest = i >> 2;
        const int r = rest % 260;
        const int cc2 = (rest / 260) & 3;
        const int bb = rest / 1040;
        int pp;
        if (r < 66)       pp = r;
        else if (r < 132) pp = 65 * 66 + (r - 66);
        else if (r < 196) pp = (r - 131) * 66;
        else              pp = (r - 195) * 66 + 65;
        f32x4 z = {0.f, 0.f, 0.f, 0.f};
        *(f32x4*)(h2p + H2P_IDX(bb, cc2, pp) + q * 8) = z;
    }

    if (i < 139392) {                    // xh: 32*4356
        const int b = i / H2P_PLANE, pp = i % H2P_PLANE;
        const int pr = pp / 66, pc = pp % 66;
        const bool interior = (pr >= 1) && (pr <= 64) && (pc >= 1) && (pc <= 64);
        _Float16 v[32];
#pragma unroll
        for (int ci = 0; ci < 32; ++ci) v[ci] = (_Float16)0.f;
        if (interior) {
            const int p = (pr - 1) * 64 + (pc - 1);
#pragma unroll
            for (int ci = 0; ci < 12; ++ci)
                v[ci] = (_Float16)x[((size_t)(b * 12 + ci) << 12) + p];
#pragma unroll
            for (int ci = 0; ci < 4; ++ci)
                v[12 + ci] = (_Float16)cond[((size_t)(b * 4 + ci) << 12) + p];
        }
        _Float16* dst = xh + ((size_t)i << 5);
#pragma unroll
        for (int q = 0; q < 4; ++q) *(f32x4*)(dst + q * 8) = *(f32x4*)(v + q * 8);
    }
}

// ---------------------------------------------------------------------------
// FUSED conv1+conv2: 128-pixel tiles, 2 blocks/CU. LDS phase-overlay: w1l
// [0,73728) lives through phase 1; w2l staged after the phase-1 barrier into
// w1l's dead upper half [36864,69632); h1l overlays [0,34816). Peak 74.2 KB.
// setprio kept (neutral-to-positive).
// ---------------------------------------------------------------------------
__global__ __launch_bounds__(256, 2) void conv12_k(
    const _Float16* __restrict__ xh, const _Float16* __restrict__ w1h,
    const _Float16* __restrict__ w2h, const float* __restrict__ b1,
    const float* __restrict__ b2, _Float16* __restrict__ h2p)
{
    __shared__ __align__(16) char smem[74240];
    // w1l [0,73728) | h1l overlay [0,34816) | w2l overlay [36864,69632)
    // b2l [73728,74240)
    float* b2l = (float*)(smem + 73728);
    _Float16* h1l = (_Float16*)smem;

    const int tid = threadIdx.x;
    const int wv = tid >> 6, lane = tid & 63;
    const int row16 = lane & 15, quad = lane >> 4;
    const int prow = wv >> 1, colb = (wv & 1) << 5;  // wv*32 = prow*64 + colb
    const int bid = blockIdx.x;            // 0..1023
    const int b = bid >> 5;
    const int pim0 = (bid & 31) << 7;      // 128-pixel tile
    const int h0 = pim0 >> 6;              // base image row (2 rows per tile)

    if (tid < 128) b2l[tid] = b2[tid];
#pragma unroll
    for (int k = 0; k < 18; ++k)                   // w1l: 4608 16B chunks
        ASYNC16(w1h + (size_t)(k * 256 + tid) * 8, smem + (k * 256 + wv * 64) * 16);

    f32x4 acc[2][8];
#pragma unroll
    for (int pt = 0; pt < 2; ++pt)
#pragma unroll
        for (int ot = 0; ot < 8; ++ot) acc[pt][ot] = (f32x4){0.f, 0.f, 0.f, 0.f};

    __syncthreads();
    const _Float16* wl = (const _Float16*)smem;

    // ---- phase 1: conv1 K-loop (no inner barriers) ----
    for (int t = 0; t < 9; ++t) {
        const int dy = t / 3, dx = t % 3;
        const int pbase = (h0 + prow + dy) * 66 + dx + colb + row16;
        half8 bf[2], af[8];
#pragma unroll
        for (int pt = 0; pt < 2; ++pt)
            bf[pt] = *(const half8*)(xh + XH_IDX(b, pbase + pt * 16) + quad * 8);
#pragma unroll
        for (int ot = 0; ot < 8; ++ot)
            af[ot] = *(const half8*)(wl + ((t * 128 + ot * 16 + row16) << 5) + quad * 8);
        __builtin_amdgcn_s_setprio(1);
#pragma unroll
        for (int ot = 0; ot < 8; ++ot)
#pragma unroll
            for (int pt = 0; pt < 2; ++pt)
                acc[pt][ot] = __builtin_amdgcn_mfma_f32_16x16x32_f16(af[ot], bf[pt], acc[pt][ot], 0, 0, 0);
        __builtin_amdgcn_s_setprio(0);
    }

    f32x4 bias[8];
#pragma unroll
    for (int ot = 0; ot < 8; ++ot) bias[ot] = *(const f32x4*)(b1 + ot * 16 + quad * 4);
    __syncthreads();                               // all w1l reads complete

    // ---- stage w2l into dead w1l region; latency hides under phase 2 ----
#pragma unroll
    for (int k = 0; k < 8; ++k)                    // 2048 16B chunks
        ASYNC16(w2h + (size_t)(k * 256 + tid) * 8, smem + 36864 + (k * 256 + wv * 64) * 16);

    // ---- phase 2: ReLU(h1+b1) -> LDS tile ----
#pragma unroll
    for (int pt = 0; pt < 2; ++pt) {
        const int pix = wv * 32 + pt * 16 + row16;
#pragma unroll
        for (int ot = 0; ot < 8; ++ot) {
            half4 v;
#pragma unroll
            for (int r = 0; r < 4; ++r)
                v[r] = (_Float16)fmaxf(acc[pt][ot][r] + bias[ot][r], 0.f);
            *(half4*)(h1l + pix * 136 + ot * 16 + quad * 4) = v;
        }
    }
#pragma unroll
    for (int pt = 0; pt < 2; ++pt)
#pragma unroll
        for (int ot = 0; ot < 8; ++ot) acc[pt][ot] = (f32x4){0.f, 0.f, 0.f, 0.f};
    __syncthreads();                               // h1l visible + w2l drained

    // ---- phase 3: conv2 K-loop (both operands LDS, no inner barriers) ----
    const _Float16* w2l = (const _Float16*)(smem + 36864);
#pragma unroll
    for (int ks = 0; ks < 4; ++ks) {
        half8 bf[2], af[8];
#pragma unroll
        for (int pt = 0; pt < 2; ++pt)
            bf[pt] = *(const half8*)(h1l + (wv * 32 + pt * 16 + row16) * 136 + ks * 32 + quad * 8);
#pragma unroll
        for (int ot = 0; ot < 8; ++ot)
            af[ot] = *(const half8*)(w2l + ((ks * 128 + ot * 16 + row16) << 5) + quad * 8);
        __builtin_amdgcn_s_setprio(1);
#pragma unroll
        for (int ot = 0; ot < 8; ++ot)
#pragma unroll
            for (int pt = 0; pt < 2; ++pt)
                acc[pt][ot] = __builtin_amdgcn_mfma_f32_16x16x32_f16(af[ot], bf[pt], acc[pt][ot], 0, 0, 0);
        __builtin_amdgcn_s_setprio(0);
    }

    // ---- epilogue: ReLU(h2+b2) -> h2p interior ----
#pragma unroll
    for (int pt = 0; pt < 2; ++pt) {
        const int p = pim0 + wv * 32 + pt * 16 + row16;      // within-image pixel
        const int pp = ((p >> 6) + 1) * 66 + (p & 63) + 1;
#pragma unroll
        for (int ot = 0; ot < 8; ++ot) {
            const int oc0 = ot * 16 + quad * 4;
            half4 v;
#pragma unroll
            for (int r = 0; r < 4; ++r)
                v[r] = (_Float16)fmaxf(acc[pt][ot][r] + b2l[oc0 + r], 0.f);
            *(half4*)(h2p + H2P_IDX(b, oc0 >> 5, pp) + (oc0 & 31)) = v;
        }
    }
}

// ---------------------------------------------------------------------------
// RQS spline evaluation: params arrive as 6 x f32x4 (bias already added).
// Fast-math scope: hw-native exp/log + one reciprocal-squared fold
// (lad = log(dnum/denom^2) as a single log); softmax/div elsewhere exact.
// ---------------------------------------------------------------------------
__device__ __forceinline__ void rqs_eval(const f32x4* pv, float xv,
                                         float& yv_out, float& lad_out)
{
#define PRM(j) (pv[(j) >> 2][(j) & 3])
    const float xin = fminf(fmaxf(xv, -3.f), 3.f);

    float mw = PRM(0), mh = PRM(8);
#pragma unroll
    for (int j = 1; j < 8; ++j) { mw = fmaxf(mw, PRM(j)); mh = fmaxf(mh, PRM(8 + j)); }
    float ew[8], eh[8];
    float sw = 0.f, sh = 0.f;
#pragma unroll
    for (int j = 0; j < 8; ++j) {
        ew[j] = __expf(PRM(j) - mw);      sw += ew[j];
        eh[j] = __expf(PRM(8 + j) - mh);  sh += eh[j];
    }
    const float rw = 1.f / sw, rh = 1.f / sh;

    const float CONST_D = 0.5397423f;    // log(exp(1-MD)-1), MD=0.001

    float cumw = 0.f, cumh = 0.f;
    float cw_lo = -3.f, ch_lo = -3.f;
    float in_cw = 0.f, in_w = 1.f, in_ch = 0.f, in_h = 1.f, sd0 = 0.f, sd1 = 0.f;
#pragma unroll
    for (int i = 0; i < 8; ++i) {
        cumw += fmaf(0.992f, ew[i] * rw, 0.001f);
        cumh += fmaf(0.992f, eh[i] * rh, 0.001f);
        const float cw_hi = (i == 7) ? 3.f : fmaf(6.f, cumw, -3.f);
        const float ch_hi = (i == 7) ? 3.f : fmaf(6.f, cumh, -3.f);
        const bool sel = (xin >= cw_lo) && ((i == 7) || (xin < cw_hi));
        in_cw = sel ? cw_lo : in_cw;
        in_w  = sel ? (cw_hi - cw_lo) : in_w;
        in_ch = sel ? ch_lo : in_ch;
        in_h  = sel ? (ch_hi - ch_lo) : in_h;
        sd0   = sel ? ((i == 0) ? CONST_D : PRM(16 + i - 1)) : sd0;
        sd1   = sel ? ((i == 7) ? CONST_D : PRM(16 + i)) : sd1;
        cw_lo = cw_hi; ch_lo = ch_hi;
    }

    const float d0 = 0.001f + ((sd0 > 20.f) ? sd0 : __logf(1.f + __expf(sd0)));
    const float d1 = 0.001f + ((sd1 > 20.f) ? sd1 : __logf(1.f + __expf(sd1)));

    const float r_inw = 1.f / in_w;
    const float delta = in_h * r_inw;
    const float theta = (xin - in_cw) * r_inw;
    const float omt = 1.f - theta;
    const float tom = theta * omt;
    const float th2 = theta * theta;
    const float numer = in_h * (delta * th2 + d0 * tom);
    const float denom = delta + (d0 + d1 - 2.f * delta) * tom;
    const float rden = 1.f / denom;
    float yv = in_ch + numer * rden;
    const float dnum = delta * delta * (d1 * th2 + 2.f * delta * tom + d0 * omt * omt);
    float lad = __logf(dnum * rden * rden);

    const bool inside = (xv >= -3.f) && (xv <= 3.f);
    yv_out = inside ? yv : xv;
    lad_out = inside ? lad : 0.f;
#undef PRM
}

// ---------------------------------------------------------------------------
// conv3 v14 (session-best): 16x16x32, row-unrolled 12 steps, N=144 (2 cols),
// acc[4][9]; launch_bounds(256,2). LDS 81,216 B: act 25,344 | wt dbuf
// 2x27,648 | b3l 576 — 2 blocks/CU. Grid 1024 = 64 groups x {2 cols x 8
// ptiles}: cols of one ptile share bid%8 -> same XCD L2 for the act region.
// GEMM: M=256 pix, N=144 of 288 oc', K=1152 (9 t x 128 ci).
// Design-space closure (r3-r14): per-MFMA LDS intensity 0.36 reads/MFMA is
// the minimum at any tile that fits the 2-wave register wall (acc>=96 =>
// 2 waves/SIMD; smaller tiles raise intensity to 0.67 => LDS-pipe-bound).
// Occupancy-force => spill (r3/r5); prefetch-touch => anti-prefetch (r9);
// direct-global bf => spill+3x fetch (r11); T14 => neutral (r12); 32x32 =>
// 2.8x bank conflicts (r13); N=144 => best (r14). Only remaining lever is
// an inline-asm 8-phase rewrite — out of risk budget for this loop.
// ---------------------------------------------------------------------------
__global__ __launch_bounds__(256, 2) void conv3_rqs_k(
    const _Float16* __restrict__ h2p, const _Float16* __restrict__ w3h,
    const float* __restrict__ b3, const float* __restrict__ x,
    float* __restrict__ y, float* __restrict__ ld_out)
{
    __shared__ __align__(16) char smem[81216];
    // act [0,25344)  wt0 [25344,52992)  wt1 [52992,80640)  b3l [80640,81216)
    // epilogue overlay: epi 4 waves x 2368 floats = [0,37888)
    float* b3l = (float*)(smem + 80640);

    const int tid = threadIdx.x;
    const int wv = tid >> 6, lane = tid & 63;
    const int row16 = lane & 15, quad = lane >> 4;
    const int bid = blockIdx.x;            // 0..1023
    const int g = bid >> 4, r = bid & 15;  // XCD swizzle: 2 cols of a ptile
    const int col = r >> 3;                // 0..1 share bid%8 (same XCD)
    const int ptile = (g << 3) | (r & 7);  // 0..511
    const int b = ptile >> 4;
    const int pim0 = (ptile & 15) << 8;
    const int h0 = pim0 >> 6;              // base row, multiple of 4

    if (tid < 144) {
        const int c = tid / 24, j = tid % 24;
        b3l[tid] = (j < 23) ? b3[(col * 6 + c) * 23 + j] : 0.f;
    }

    f32x4 acc[4][9];
#pragma unroll
    for (int pt = 0; pt < 4; ++pt)
#pragma unroll
        for (int ot = 0; ot < 9; ++ot) acc[pt][ot] = (f32x4){0.f, 0.f, 0.f, 0.f};

    // ---- staging helpers (contiguous global->LDS via global_load_lds) ----
    // stage one filter row (3 taps) for (dy, cc): 3 x 9216 B into wt buf
    auto stage_wt3 = [&](int dy, int cc, int buf) {
#pragma unroll
        for (int j = 0; j < 3; ++j) {
            const int t = dy * 3 + j;
            const _Float16* gp = w3h + ((size_t)((t * 4 + cc) * 288 + col * 144) << 5);
            char* wb = smem + 25344 + buf * 27648 + j * 9216;   // 576 chunks
            ASYNC16(gp + (size_t)tid * 8, wb + wv * 64 * 16);
            ASYNC16(gp + (size_t)(256 + tid) * 8, wb + (256 + wv * 64) * 16);
            if (wv == 0) ASYNC16(gp + (size_t)(512 + lane) * 8, wb + 512 * 16);
        }
    };
    auto stage_act = [&](int cc) {
        const _Float16* ga = h2p + H2P_IDX(b, cc, h0 * 66);   // 25344 B contiguous
#pragma unroll
        for (int k = 0; k < 6; ++k)
            ASYNC16(ga + (size_t)(k * 256 + tid) * 8, smem + (k * 256 + wv * 64) * 16);
        if (wv == 0 && lane < 48)
            ASYNC16(ga + (size_t)(1536 + lane) * 8, smem + 1536 * 16);
    };

    stage_act(0);
    stage_wt3(0, 0, 0);

    for (int cc = 0; cc < 4; ++cc) {
        for (int dy = 0; dy < 3; ++dy) {
            const int step = cc * 3 + dy;
            __syncthreads();               // staged data ready; other wt buf free
            if (step + 1 < 12)
                stage_wt3((dy == 2) ? 0 : dy + 1, (dy == 2) ? cc + 1 : cc, (step + 1) & 1);
            const _Float16* act = (const _Float16*)smem;
            const _Float16* wt = (const _Float16*)(smem + 25344 + (step & 1) * 27648);
            const int lrow = (wv + dy) * 66 + row16;
#pragma unroll
            for (int dx = 0; dx < 3; ++dx) {
                half8 bf[4], af[9];
#pragma unroll
                for (int pt = 0; pt < 4; ++pt)
                    bf[pt] = *(const half8*)(act + ((lrow + dx + pt * 16) << 5) + quad * 8);
#pragma unroll
                for (int ot = 0; ot < 9; ++ot)
                    af[ot] = *(const half8*)(wt + dx * 4608 + ((ot * 16 + row16) << 5) + quad * 8);
#pragma unroll
                for (int ot = 0; ot < 9; ++ot)
#pragma unroll
                    for (int pt = 0; pt < 4; ++pt)
                        acc[pt][ot] = __builtin_amdgcn_mfma_f32_16x16x32_f16(af[ot], bf[pt], acc[pt][ot], 0, 0, 0);
            }
            if (dy == 2 && cc < 3) {
                __syncthreads();           // act buffer dead for all waves
                stage_act(cc + 1);
            }
        }
    }
    __syncthreads();   // K-loop LDS reads done (all waves); epi overlay safe

    // ---- epilogue: wave-private epi slice; no cross-wave barriers needed ----
    float* epi = (float*)smem + wv * 2368;     // 16 pix x 148-stride floats
    float lad_acc = 0.f;
#pragma unroll
    for (int pt = 0; pt < 4; ++pt) {
#pragma unroll
        for (int ot = 0; ot < 9; ++ot)
            *(f32x4*)(epi + row16 * 148 + ot * 16 + quad * 4) = acc[pt][ot];
        // own-wave ds_writes complete before the dependent ds_reads below
        asm volatile("s_waitcnt lgkmcnt(0)" ::: "memory");
        __builtin_amdgcn_sched_barrier(0);     // rule #18: pin ops after the wait
#pragma unroll 1
        for (int pass = 0; pass < 2; ++pass) {
            const int idx = pass * 64 + lane;
            if (idx < 96) {
                const int p16 = idx & 15, c = idx >> 4;       // c 0..5
                const float* pb = epi + p16 * 148 + c * 24;
                const float* bb = b3l + c * 24;
                f32x4 pv[6];
#pragma unroll
                for (int q = 0; q < 6; ++q)
                    pv[q] = *(const f32x4*)(pb + q * 4) + *(const f32x4*)(bb + q * 4);
                const int tpix = wv * 64 + pt * 16 + p16;
                const size_t xi = (((size_t)(b * 12 + col * 6 + c)) << 12) + (pim0 + tpix);
                const float xv = x[xi];
                float yv, lad;
                rqs_eval(pv, xv, yv, lad);
                y[xi] = yv;
                lad_acc += lad;
            }
        }
        // reads of this pt complete before next pt's writes reuse the slice
        asm volatile("s_waitcnt lgkmcnt(0)" ::: "memory");
        __builtin_amdgcn_sched_barrier(0);
    }

#pragma unroll
    for (int off = 32; off > 0; off >>= 1) lad_acc += __shfl_down(lad_acc, off);
    if (lane == 0) atomicAdd(&ld_out[b], lad_acc);
}

// ---------------------------------------------------------------------------
// Workspace layout COMPACTED (round 17): the 33.5 MB h1p slot died with the
// round-7 conv1+conv2 fusion but the layout still reserved it. Touched
// footprint 70 MB -> 45.4 MB; if the harness restores/clears workspace
// between iterations this saves ~25 MB of per-iter traffic, else neutral.
// All regions disjoint, 16B-aligned.
// ---------------------------------------------------------------------------
extern "C" void kernel_launch(void* const* d_in, const int* in_sizes, int n_in,
                              void* d_out, int out_size, void* d_ws, size_t ws_size,
                              hipStream_t stream)
{
    const float* x      = (const float*)d_in[0];
    const float* logdet = (const float*)d_in[1];
    const float* cond   = (const float*)d_in[2];
    const float* w1     = (const float*)d_in[3];
    const float* b1     = (const float*)d_in[4];
    const float* w2     = (const float*)d_in[5];
    const float* b2     = (const float*)d_in[6];
    const float* w3     = (const float*)d_in[7];
    const float* b3     = (const float*)d_in[8];

    char* ws = (char*)d_ws;
    _Float16* xh  = (_Float16*)ws;                       // [0, 8,921,088)
    _Float16* h2p = (_Float16*)(ws + 8921088);           // [8,921,088, 44,605,440)
    _Float16* w1h = (_Float16*)(ws + 44605440);          // 73,728 B
    _Float16* w2h = (_Float16*)(ws + 44679168);          // 32,768 B
    _Float16* w3h = (_Float16*)(ws + 44711936);          // 663,552 B (end 45,375,488)

    float* y      = (float*)d_out;                       // NY floats
    float* ld_out = y + NY;                              // 32 floats

    prep_xh_k<<<1296, 256, 0, stream>>>(w1, w2, w3, w1h, w2h, w3h, logdet, ld_out, x, cond, xh, h2p);
    conv12_k<<<1024, 256, 0, stream>>>(xh, w1h, w2h, b1, b2, h2p);
    conv3_rqs_k<<<1024, 256, 0, stream>>>(h2p, w3h, b3, x, y, ld_out);
}

// Round 18
// 200.244 us; speedup vs baseline: 1.0241x; 1.0241x over previous
//
#include <hip/hip_runtime.h>
#include <math.h>

// B=32, C=12, H=64, W=64, hidden=128, cond_c=4, out_spline=276 (pad->288=12*24)
// NUM_BINS=8, TAIL=3.0, MBW=MBH=MD=0.001

#define NY   1572864

typedef _Float16 half8 __attribute__((ext_vector_type(8)));
typedef _Float16 half4 __attribute__((ext_vector_type(4)));
typedef float f32x4 __attribute__((ext_vector_type(4)));

// async global->LDS, 16B per lane: HW writes LDS base + lane*16; lds base wave-uniform
#define ASYNC16(gsrc, ldst) \
  __builtin_amdgcn_global_load_lds((const __attribute__((address_space(1))) unsigned int*)(gsrc), \
                                   (__attribute__((address_space(3))) unsigned int*)(ldst), 16, 0, 0)

// h2p layout: [b][cc=ci/32][pp=66*66][ci%32] fp16, halo ring of zeros
#define H2P_PLANE 4356            // 66*66
#define H2P_IDX(b, cc, pp) ((((size_t)(b) * 4 + (cc)) * H2P_PLANE + (pp)) << 5)
// xh layout: [b][pp=66*66][32] fp16 (ci<12 x, 12..15 cond, >=16 zero; halo zero)
#define XH_IDX(b, pp) (((size_t)(b) * H2P_PLANE + (pp)) << 5)

// ---------------------------------------------------------------------------
// prep + xh + halo-ring zero (merged):
//   w1 (128,16,3,3)  -> w1h[(t*128+oc)*32 + k]   k=ci<16 real, k>=16 zero   fp16
//   w2 (128,128,1,1) -> w2h[(ks*128+oc)*32 + km]  (ci=ks*32+km)             fp16
//   w3 (276,128,3,3) -> w3h[((t*4+cc)*288 + oc')*32 + cim]                  fp16
//                       oc' = c*24 + j (j<23 real, j=23 zero pad)
//   xh: pack x(12ch fp32) + cond(4ch fp32) into halo-padded fp16 [b][66*66][32]
// ---------------------------------------------------------------------------
__global__ __launch_bounds__(256) void prep_xh_k(
    const float* __restrict__ w1, const float* __restrict__ w2,
    const float* __restrict__ w3, _Float16* __restrict__ w1h,
    _Float16* __restrict__ w2h, _Float16* __restrict__ w3h,
    const float* __restrict__ logdet, float* __restrict__ ld_out,
    const float* __restrict__ x, const float* __restrict__ cond,
    _Float16* __restrict__ xh, _Float16* __restrict__ h2p)
{
    const int i = blockIdx.x * 256 + threadIdx.x;   // < 331776
    if (i < 36864) {                     // w1h
        int k = i & 31, oc = (i >> 5) & 127, t = i >> 12;
        w1h[i] = (_Float16)((k < 16) ? w1[(oc * 16 + k) * 9 + t] : 0.f);
    }
    if (i < 16384) {                     // w2h
        int km = i & 31, oc = (i >> 5) & 127, ks = i >> 12;
        w2h[i] = (_Float16)w2[oc * 128 + ks * 32 + km];
    }
    {   // w3h: flat i = ((t*4+cc)*288 + oc)*32 + cim
        int cim = i & 31;
        int oc = (i >> 5) % 288;
        int tc = i / (288 * 32);        // 0..35
        int t = tc >> 2, cc = tc & 3;
        int c = oc / 24, j = oc % 24;
        int ci = cc * 32 + cim;
        float v = (j < 23) ? w3[((c * 23 + j) * 128 + ci) * 9 + t] : 0.f;
        w3h[i] = (_Float16)v;
    }
    if (i < 32) ld_out[i] = logdet[i];

    if (i < 133120) {                    // h2p halo-ring zero
        const int q = i & 3;
        const int rest = i >> 2;
        const int r = rest % 260;
        const int cc2 = (rest / 260) & 3;
        const int bb = rest / 1040;
        int pp;
        if (r < 66)       pp = r;
        else if (r < 132) pp = 65 * 66 + (r - 66);
        else if (r < 196) pp = (r - 131) * 66;
        else              pp = (r - 195) * 66 + 65;
        f32x4 z = {0.f, 0.f, 0.f, 0.f};
        *(f32x4*)(h2p + H2P_IDX(bb, cc2, pp) + q * 8) = z;
    }

    if (i < 139392) {                    // xh: 32*4356
        const int b = i / H2P_PLANE, pp = i % H2P_PLANE;
        const int pr = pp / 66, pc = pp % 66;
        const bool interior = (pr >= 1) && (pr <= 64) && (pc >= 1) && (pc <= 64);
        _Float16 v[32];
#pragma unroll
        for (int ci = 0; ci < 32; ++ci) v[ci] = (_Float16)0.f;
        if (interior) {
            const int p = (pr - 1) * 64 + (pc - 1);
#pragma unroll
            for (int ci = 0; ci < 12; ++ci)
                v[ci] = (_Float16)x[((size_t)(b * 12 + ci) << 12) + p];
#pragma unroll
            for (int ci = 0; ci < 4; ++ci)
                v[12 + ci] = (_Float16)cond[((size_t)(b * 4 + ci) << 12) + p];
        }
        _Float16* dst = xh + ((size_t)i << 5);
#pragma unroll
        for (int q = 0; q < 4; ++q) *(f32x4*)(dst + q * 8) = *(f32x4*)(v + q * 8);
    }
}

// ---------------------------------------------------------------------------
// FUSED conv1+conv2: 128-pixel tiles, 2 blocks/CU. LDS phase-overlay: w1l
// [0,73728) lives through phase 1; w2l staged after the phase-1 barrier into
// w1l's dead upper half [36864,69632); h1l overlays [0,34816). Peak 74.2 KB.
// setprio kept (neutral-to-positive).
// ---------------------------------------------------------------------------
__global__ __launch_bounds__(256, 2) void conv12_k(
    const _Float16* __restrict__ xh, const _Float16* __restrict__ w1h,
    const _Float16* __restrict__ w2h, const float* __restrict__ b1,
    const float* __restrict__ b2, _Float16* __restrict__ h2p)
{
    __shared__ __align__(16) char smem[74240];
    // w1l [0,73728) | h1l overlay [0,34816) | w2l overlay [36864,69632)
    // b2l [73728,74240)
    float* b2l = (float*)(smem + 73728);
    _Float16* h1l = (_Float16*)smem;

    const int tid = threadIdx.x;
    const int wv = tid >> 6, lane = tid & 63;
    const int row16 = lane & 15, quad = lane >> 4;
    const int prow = wv >> 1, colb = (wv & 1) << 5;  // wv*32 = prow*64 + colb
    const int bid = blockIdx.x;            // 0..1023
    const int b = bid >> 5;
    const int pim0 = (bid & 31) << 7;      // 128-pixel tile
    const int h0 = pim0 >> 6;              // base image row (2 rows per tile)

    if (tid < 128) b2l[tid] = b2[tid];
#pragma unroll
    for (int k = 0; k < 18; ++k)                   // w1l: 4608 16B chunks
        ASYNC16(w1h + (size_t)(k * 256 + tid) * 8, smem + (k * 256 + wv * 64) * 16);

    f32x4 acc[2][8];
#pragma unroll
    for (int pt = 0; pt < 2; ++pt)
#pragma unroll
        for (int ot = 0; ot < 8; ++ot) acc[pt][ot] = (f32x4){0.f, 0.f, 0.f, 0.f};

    __syncthreads();
    const _Float16* wl = (const _Float16*)smem;

    // ---- phase 1: conv1 K-loop (no inner barriers) ----
    for (int t = 0; t < 9; ++t) {
        const int dy = t / 3, dx = t % 3;
        const int pbase = (h0 + prow + dy) * 66 + dx + colb + row16;
        half8 bf[2], af[8];
#pragma unroll
        for (int pt = 0; pt < 2; ++pt)
            bf[pt] = *(const half8*)(xh + XH_IDX(b, pbase + pt * 16) + quad * 8);
#pragma unroll
        for (int ot = 0; ot < 8; ++ot)
            af[ot] = *(const half8*)(wl + ((t * 128 + ot * 16 + row16) << 5) + quad * 8);
        __builtin_amdgcn_s_setprio(1);
#pragma unroll
        for (int ot = 0; ot < 8; ++ot)
#pragma unroll
            for (int pt = 0; pt < 2; ++pt)
                acc[pt][ot] = __builtin_amdgcn_mfma_f32_16x16x32_f16(af[ot], bf[pt], acc[pt][ot], 0, 0, 0);
        __builtin_amdgcn_s_setprio(0);
    }

    f32x4 bias[8];
#pragma unroll
    for (int ot = 0; ot < 8; ++ot) bias[ot] = *(const f32x4*)(b1 + ot * 16 + quad * 4);
    __syncthreads();                               // all w1l reads complete

    // ---- stage w2l into dead w1l region; latency hides under phase 2 ----
#pragma unroll
    for (int k = 0; k < 8; ++k)                    // 2048 16B chunks
        ASYNC16(w2h + (size_t)(k * 256 + tid) * 8, smem + 36864 + (k * 256 + wv * 64) * 16);

    // ---- phase 2: ReLU(h1+b1) -> LDS tile ----
#pragma unroll
    for (int pt = 0; pt < 2; ++pt) {
        const int pix = wv * 32 + pt * 16 + row16;
#pragma unroll
        for (int ot = 0; ot < 8; ++ot) {
            half4 v;
#pragma unroll
            for (int r = 0; r < 4; ++r)
                v[r] = (_Float16)fmaxf(acc[pt][ot][r] + bias[ot][r], 0.f);
            *(half4*)(h1l + pix * 136 + ot * 16 + quad * 4) = v;
        }
    }
#pragma unroll
    for (int pt = 0; pt < 2; ++pt)
#pragma unroll
        for (int ot = 0; ot < 8; ++ot) acc[pt][ot] = (f32x4){0.f, 0.f, 0.f, 0.f};
    __syncthreads();                               // h1l visible + w2l drained

    // ---- phase 3: conv2 K-loop (both operands LDS, no inner barriers) ----
    const _Float16* w2l = (const _Float16*)(smem + 36864);
#pragma unroll
    for (int ks = 0; ks < 4; ++ks) {
        half8 bf[2], af[8];
#pragma unroll
        for (int pt = 0; pt < 2; ++pt)
            bf[pt] = *(const half8*)(h1l + (wv * 32 + pt * 16 + row16) * 136 + ks * 32 + quad * 8);
#pragma unroll
        for (int ot = 0; ot < 8; ++ot)
            af[ot] = *(const half8*)(w2l + ((ks * 128 + ot * 16 + row16) << 5) + quad * 8);
        __builtin_amdgcn_s_setprio(1);
#pragma unroll
        for (int ot = 0; ot < 8; ++ot)
#pragma unroll
            for (int pt = 0; pt < 2; ++pt)
                acc[pt][ot] = __builtin_amdgcn_mfma_f32_16x16x32_f16(af[ot], bf[pt], acc[pt][ot], 0, 0, 0);
        __builtin_amdgcn_s_setprio(0);
    }

    // ---- epilogue: ReLU(h2+b2) -> h2p interior ----
#pragma unroll
    for (int pt = 0; pt < 2; ++pt) {
        const int p = pim0 + wv * 32 + pt * 16 + row16;      // within-image pixel
        const int pp = ((p >> 6) + 1) * 66 + (p & 63) + 1;
#pragma unroll
        for (int ot = 0; ot < 8; ++ot) {
            const int oc0 = ot * 16 + quad * 4;
            half4 v;
#pragma unroll
            for (int r = 0; r < 4; ++r)
                v[r] = (_Float16)fmaxf(acc[pt][ot][r] + b2l[oc0 + r], 0.f);
            *(half4*)(h2p + H2P_IDX(b, oc0 >> 5, pp) + (oc0 & 31)) = v;
        }
    }
}

// ---------------------------------------------------------------------------
// RQS spline evaluation: params arrive as 6 x f32x4 (bias already added).
// Fast-math scope: hw-native exp/log + one reciprocal-squared fold
// (lad = log(dnum/denom^2) as a single log); softmax/div elsewhere exact.
// ---------------------------------------------------------------------------
__device__ __forceinline__ void rqs_eval(const f32x4* pv, float xv,
                                         float& yv_out, float& lad_out)
{
#define PRM(j) (pv[(j) >> 2][(j) & 3])
    const float xin = fminf(fmaxf(xv, -3.f), 3.f);

    float mw = PRM(0), mh = PRM(8);
#pragma unroll
    for (int j = 1; j < 8; ++j) { mw = fmaxf(mw, PRM(j)); mh = fmaxf(mh, PRM(8 + j)); }
    float ew[8], eh[8];
    float sw = 0.f, sh = 0.f;
#pragma unroll
    for (int j = 0; j < 8; ++j) {
        ew[j] = __expf(PRM(j) - mw);      sw += ew[j];
        eh[j] = __expf(PRM(8 + j) - mh);  sh += eh[j];
    }
    const float rw = 1.f / sw, rh = 1.f / sh;

    const float CONST_D = 0.5397423f;    // log(exp(1-MD)-1), MD=0.001

    float cumw = 0.f, cumh = 0.f;
    float cw_lo = -3.f, ch_lo = -3.f;
    float in_cw = 0.f, in_w = 1.f, in_ch = 0.f, in_h = 1.f, sd0 = 0.f, sd1 = 0.f;
#pragma unroll
    for (int i = 0; i < 8; ++i) {
        cumw += fmaf(0.992f, ew[i] * rw, 0.001f);
        cumh += fmaf(0.992f, eh[i] * rh, 0.001f);
        const float cw_hi = (i == 7) ? 3.f : fmaf(6.f, cumw, -3.f);
        const float ch_hi = (i == 7) ? 3.f : fmaf(6.f, cumh, -3.f);
        const bool sel = (xin >= cw_lo) && ((i == 7) || (xin < cw_hi));
        in_cw = sel ? cw_lo : in_cw;
        in_w  = sel ? (cw_hi - cw_lo) : in_w;
        in_ch = sel ? ch_lo : in_ch;
        in_h  = sel ? (ch_hi - ch_lo) : in_h;
        sd0   = sel ? ((i == 0) ? CONST_D : PRM(16 + i - 1)) : sd0;
        sd1   = sel ? ((i == 7) ? CONST_D : PRM(16 + i)) : sd1;
        cw_lo = cw_hi; ch_lo = ch_hi;
    }

    const float d0 = 0.001f + ((sd0 > 20.f) ? sd0 : __logf(1.f + __expf(sd0)));
    const float d1 = 0.001f + ((sd1 > 20.f) ? sd1 : __logf(1.f + __expf(sd1)));

    const float r_inw = 1.f / in_w;
    const float delta = in_h * r_inw;
    const float theta = (xin - in_cw) * r_inw;
    const float omt = 1.f - theta;
    const float tom = theta * omt;
    const float th2 = theta * theta;
    const float numer = in_h * (delta * th2 + d0 * tom);
    const float denom = delta + (d0 + d1 - 2.f * delta) * tom;
    const float rden = 1.f / denom;
    float yv = in_ch + numer * rden;
    const float dnum = delta * delta * (d1 * th2 + 2.f * delta * tom + d0 * omt * omt);
    float lad = __logf(dnum * rden * rden);

    const bool inside = (xv >= -3.f) && (xv <= 3.f);
    yv_out = inside ? yv : xv;
    lad_out = inside ? lad : 0.f;
#undef PRM
}

// ---------------------------------------------------------------------------
// conv3 v15: v14 K-loop unchanged; epilogue LANE-PACKED — two pt-slices per
// phase (epi 2x2368 floats/wave = 75,776 B total, fits under b3l at 80,640),
// so the 192 items (2 pt x 16 pix x 6 ch) fill exactly 3 full 64-lane
// passes (was: 2 passes/pt with pass 2 half-idle -> 16 passes of latency
// for 12 passes of work, 8 fences). Now 6 full passes + 4 fences total.
// All epi accesses remain wave-private; acc indices statically unrolled.
// K-loop/geometry per v14: 16x16x32, 12 row-steps, N=144, acc[4][9],
// launch_bounds(256,2), LDS 81,216 B, 2 blocks/CU. Grid 1024 = 64 groups x
// {2 cols x 8 ptiles} (col-pair shares XCD L2 for the act region).
// Design-space closure (r3-r14) documented in session journal.
// ---------------------------------------------------------------------------
__global__ __launch_bounds__(256, 2) void conv3_rqs_k(
    const _Float16* __restrict__ h2p, const _Float16* __restrict__ w3h,
    const float* __restrict__ b3, const float* __restrict__ x,
    float* __restrict__ y, float* __restrict__ ld_out)
{
    __shared__ __align__(16) char smem[81216];
    // act [0,25344)  wt0 [25344,52992)  wt1 [52992,80640)  b3l [80640,81216)
    // epilogue overlay: epi 4 waves x 4736 floats = [0,75776)
    float* b3l = (float*)(smem + 80640);

    const int tid = threadIdx.x;
    const int wv = tid >> 6, lane = tid & 63;
    const int row16 = lane & 15, quad = lane >> 4;
    const int bid = blockIdx.x;            // 0..1023
    const int g = bid >> 4, r = bid & 15;  // XCD swizzle: 2 cols of a ptile
    const int col = r >> 3;                // 0..1 share bid%8 (same XCD)
    const int ptile = (g << 3) | (r & 7);  // 0..511
    const int b = ptile >> 4;
    const int pim0 = (ptile & 15) << 8;
    const int h0 = pim0 >> 6;              // base row, multiple of 4

    if (tid < 144) {
        const int c = tid / 24, j = tid % 24;
        b3l[tid] = (j < 23) ? b3[(col * 6 + c) * 23 + j] : 0.f;
    }

    f32x4 acc[4][9];
#pragma unroll
    for (int pt = 0; pt < 4; ++pt)
#pragma unroll
        for (int ot = 0; ot < 9; ++ot) acc[pt][ot] = (f32x4){0.f, 0.f, 0.f, 0.f};

    // ---- staging helpers (contiguous global->LDS via global_load_lds) ----
    // stage one filter row (3 taps) for (dy, cc): 3 x 9216 B into wt buf
    auto stage_wt3 = [&](int dy, int cc, int buf) {
#pragma unroll
        for (int j = 0; j < 3; ++j) {
            const int t = dy * 3 + j;
            const _Float16* gp = w3h + ((size_t)((t * 4 + cc) * 288 + col * 144) << 5);
            char* wb = smem + 25344 + buf * 27648 + j * 9216;   // 576 chunks
            ASYNC16(gp + (size_t)tid * 8, wb + wv * 64 * 16);
            ASYNC16(gp + (size_t)(256 + tid) * 8, wb + (256 + wv * 64) * 16);
            if (wv == 0) ASYNC16(gp + (size_t)(512 + lane) * 8, wb + 512 * 16);
        }
    };
    auto stage_act = [&](int cc) {
        const _Float16* ga = h2p + H2P_IDX(b, cc, h0 * 66);   // 25344 B contiguous
#pragma unroll
        for (int k = 0; k < 6; ++k)
            ASYNC16(ga + (size_t)(k * 256 + tid) * 8, smem + (k * 256 + wv * 64) * 16);
        if (wv == 0 && lane < 48)
            ASYNC16(ga + (size_t)(1536 + lane) * 8, smem + 1536 * 16);
    };

    stage_act(0);
    stage_wt3(0, 0, 0);

    for (int cc = 0; cc < 4; ++cc) {
        for (int dy = 0; dy < 3; ++dy) {
            const int step = cc * 3 + dy;
            __syncthreads();               // staged data ready; other wt buf free
            if (step + 1 < 12)
                stage_wt3((dy == 2) ? 0 : dy + 1, (dy == 2) ? cc + 1 : cc, (step + 1) & 1);
            const _Float16* act = (const _Float16*)smem;
            const _Float16* wt = (const _Float16*)(smem + 25344 + (step & 1) * 27648);
            const int lrow = (wv + dy) * 66 + row16;
#pragma unroll
            for (int dx = 0; dx < 3; ++dx) {
                half8 bf[4], af[9];
#pragma unroll
                for (int pt = 0; pt < 4; ++pt)
                    bf[pt] = *(const half8*)(act + ((lrow + dx + pt * 16) << 5) + quad * 8);
#pragma unroll
                for (int ot = 0; ot < 9; ++ot)
                    af[ot] = *(const half8*)(wt + dx * 4608 + ((ot * 16 + row16) << 5) + quad * 8);
#pragma unroll
                for (int ot = 0; ot < 9; ++ot)
#pragma unroll
                    for (int pt = 0; pt < 4; ++pt)
                        acc[pt][ot] = __builtin_amdgcn_mfma_f32_16x16x32_f16(af[ot], bf[pt], acc[pt][ot], 0, 0, 0);
            }
            if (dy == 2 && cc < 3) {
                __syncthreads();           // act buffer dead for all waves
                stage_act(cc + 1);
            }
        }
    }
    __syncthreads();   // K-loop LDS reads done (all waves); epi overlay safe

    // ---- epilogue: wave-private epi slice; 2 pt-slices per phase ----
    float* epi = (float*)smem + wv * 4736;     // 2 x (16 pix x 148 floats)
    float lad_acc = 0.f;
#pragma unroll
    for (int ph = 0; ph < 2; ++ph) {           // pt pairs {0,1}, {2,3}
#pragma unroll
        for (int ptq = 0; ptq < 2; ++ptq)
#pragma unroll
            for (int ot = 0; ot < 9; ++ot)
                *(f32x4*)(epi + ptq * 2368 + row16 * 148 + ot * 16 + quad * 4)
                    = acc[ph * 2 + ptq][ot];
        // own-wave ds_writes complete before the dependent ds_reads below
        asm volatile("s_waitcnt lgkmcnt(0)" ::: "memory");
        __builtin_amdgcn_sched_barrier(0);     // rule #18: pin ops after the wait
#pragma unroll 1
        for (int pass = 0; pass < 3; ++pass) {
            const int idx = pass * 64 + lane;          // 0..191, all lanes live
            const int ptq = (idx >= 96) ? 1 : 0;
            const int rem = idx - ptq * 96;
            const int p16 = rem & 15, c = rem >> 4;    // c 0..5
            const float* pb = epi + ptq * 2368 + p16 * 148 + c * 24;
            const float* bb = b3l + c * 24;
            f32x4 pv[6];
#pragma unroll
            for (int q = 0; q < 6; ++q)
                pv[q] = *(const f32x4*)(pb + q * 4) + *(const f32x4*)(bb + q * 4);
            const int tpix = wv * 64 + (ph * 2 + ptq) * 16 + p16;
            const size_t xi = (((size_t)(b * 12 + col * 6 + c)) << 12) + (pim0 + tpix);
            const float xv = x[xi];
            float yv, lad;
            rqs_eval(pv, xv, yv, lad);
            y[xi] = yv;
            lad_acc += lad;
        }
        // reads of this phase complete before next phase's writes reuse epi
        asm volatile("s_waitcnt lgkmcnt(0)" ::: "memory");
        __builtin_amdgcn_sched_barrier(0);
    }

#pragma unroll
    for (int off = 32; off > 0; off >>= 1) lad_acc += __shfl_down(lad_acc, off);
    if (lane == 0) atomicAdd(&ld_out[b], lad_acc);
}

// ---------------------------------------------------------------------------
extern "C" void kernel_launch(void* const* d_in, const int* in_sizes, int n_in,
                              void* d_out, int out_size, void* d_ws, size_t ws_size,
                              hipStream_t stream)
{
    const float* x      = (const float*)d_in[0];
    const float* logdet = (const float*)d_in[1];
    const float* cond   = (const float*)d_in[2];
    const float* w1     = (const float*)d_in[3];
    const float* b1     = (const float*)d_in[4];
    const float* w2     = (const float*)d_in[5];
    const float* b2     = (const float*)d_in[6];
    const float* w3     = (const float*)d_in[7];
    const float* b3     = (const float*)d_in[8];

    char* ws = (char*)d_ws;
    _Float16* xh  = (_Float16*)ws;                       // 8,921,088 B
    _Float16* h2p = (_Float16*)(ws + 33554432);          // 35,684,352 B
    _Float16* w1h = (_Float16*)(ws + 69238784);          // 73,728 B
    _Float16* w2h = (_Float16*)(ws + 69312512);          // 32,768 B
    _Float16* w3h = (_Float16*)(ws + 69345280);          // 663,552 B (end ~70 MB)

    float* y      = (float*)d_out;                       // NY floats
    float* ld_out = y + NY;                              // 32 floats

    prep_xh_k<<<1296, 256, 0, stream>>>(w1, w2, w3, w1h, w2h, w3h, logdet, ld_out, x, cond, xh, h2p);
    conv12_k<<<1024, 256, 0, stream>>>(xh, w1h, w2h, b1, b2, h2p);
    conv3_rqs_k<<<1024, 256, 0, stream>>>(h2p, w3h, b3, x, y, ld_out);
}

// Round 19
// 194.189 us; speedup vs baseline: 1.0560x; 1.0312x over previous
//
#include <hip/hip_runtime.h>
#include <math.h>

// B=32, C=12, H=64, W=64, hidden=128, cond_c=4, out_spline=276 (pad->288=12*24)
// NUM_BINS=8, TAIL=3.0, MBW=MBH=MD=0.001

#define NY   1572864

typedef _Float16 half8 __attribute__((ext_vector_type(8)));
typedef _Float16 half4 __attribute__((ext_vector_type(4)));
typedef float f32x4 __attribute__((ext_vector_type(4)));

// async global->LDS, 16B per lane: HW writes LDS base + lane*16; lds base wave-uniform
#define ASYNC16(gsrc, ldst) \
  __builtin_amdgcn_global_load_lds((const __attribute__((address_space(1))) unsigned int*)(gsrc), \
                                   (__attribute__((address_space(3))) unsigned int*)(ldst), 16, 0, 0)

// h2p layout: [b][cc=ci/32][pp=66*66][ci%32] fp16, halo ring of zeros
#define H2P_PLANE 4356            // 66*66
#define H2P_IDX(b, cc, pp) ((((size_t)(b) * 4 + (cc)) * H2P_PLANE + (pp)) << 5)
// xh layout (DENSE, round 19): [b][pp=66*66][16] fp16 — ci<12 x, 12..15 cond;
// halo rows/cols zero. 16 real channels exactly fill K/2 of one MFMA.
#define XH_IDX(b, pp) (((size_t)(b) * H2P_PLANE + (pp)) << 4)

// ---------------------------------------------------------------------------
// prep + xh + halo-ring zero (merged):
//   w1 (128,16,3,3) -> w1p DENSE TAP-PAIRED: s=0..4 packs taps (2s,2s+1)
//     w1p[(s*128+oc)*32 + k]: k<16 -> tap 2s, ci=k; k>=16 -> tap 2s+1,
//     ci=k-16 (s=4: k<16 tap 8, k>=16 zero pad). 20,480 halves = 40,960 B.
//   w2 (128,128,1,1) -> w2h[(ks*128+oc)*32 + km]  (ci=ks*32+km)        fp16
//   w3 (276,128,3,3) -> w3h[((t*4+cc)*288 + oc')*32 + cim]             fp16
//                       oc' = c*24 + j (j<23 real, j=23 zero pad)
//   xh: pack x(12ch) + cond(4ch) into halo-padded fp16 [b][66*66][16]
// ---------------------------------------------------------------------------
__global__ __launch_bounds__(256) void prep_xh_k(
    const float* __restrict__ w1, const float* __restrict__ w2,
    const float* __restrict__ w3, _Float16* __restrict__ w1p,
    _Float16* __restrict__ w2h, _Float16* __restrict__ w3h,
    const float* __restrict__ logdet, float* __restrict__ ld_out,
    const float* __restrict__ x, const float* __restrict__ cond,
    _Float16* __restrict__ xh, _Float16* __restrict__ h2p)
{
    const int i = blockIdx.x * 256 + threadIdx.x;   // < 331776
    if (i < 20480) {                     // w1p (dense tap-pair pack)
        int k = i & 31, oc = (i >> 5) & 127, s = i >> 12;   // s 0..4
        float v;
        if (s < 4) {
            int t = 2 * s + (k >> 4), ci = k & 15;
            v = w1[(oc * 16 + ci) * 9 + t];
        } else {
            v = (k < 16) ? w1[(oc * 16 + k) * 9 + 8] : 0.f;
        }
        w1p[i] = (_Float16)v;
    }
    if (i < 16384) {                     // w2h
        int km = i & 31, oc = (i >> 5) & 127, ks = i >> 12;
        w2h[i] = (_Float16)w2[oc * 128 + ks * 32 + km];
    }
    {   // w3h: flat i = ((t*4+cc)*288 + oc)*32 + cim
        int cim = i & 31;
        int oc = (i >> 5) % 288;
        int tc = i / (288 * 32);        // 0..35
        int t = tc >> 2, cc = tc & 3;
        int c = oc / 24, j = oc % 24;
        int ci = cc * 32 + cim;
        float v = (j < 23) ? w3[((c * 23 + j) * 128 + ci) * 9 + t] : 0.f;
        w3h[i] = (_Float16)v;
    }
    if (i < 32) ld_out[i] = logdet[i];

    if (i < 133120) {                    // h2p halo-ring zero
        const int q = i & 3;
        const int rest = i >> 2;
        const int r = rest % 260;
        const int cc2 = (rest / 260) & 3;
        const int bb = rest / 1040;
        int pp;
        if (r < 66)       pp = r;
        else if (r < 132) pp = 65 * 66 + (r - 66);
        else if (r < 196) pp = (r - 131) * 66;
        else              pp = (r - 195) * 66 + 65;
        f32x4 z = {0.f, 0.f, 0.f, 0.f};
        *(f32x4*)(h2p + H2P_IDX(bb, cc2, pp) + q * 8) = z;
    }

    if (i < 139392) {                    // xh: 32*4356, 16 halves each
        const int b = i / H2P_PLANE, pp = i % H2P_PLANE;
        const int pr = pp / 66, pc = pp % 66;
        const bool interior = (pr >= 1) && (pr <= 64) && (pc >= 1) && (pc <= 64);
        _Float16 v[16];
#pragma unroll
        for (int ci = 0; ci < 16; ++ci) v[ci] = (_Float16)0.f;
        if (interior) {
            const int p = (pr - 1) * 64 + (pc - 1);
#pragma unroll
            for (int ci = 0; ci < 12; ++ci)
                v[ci] = (_Float16)x[((size_t)(b * 12 + ci) << 12) + p];
#pragma unroll
            for (int ci = 0; ci < 4; ++ci)
                v[12 + ci] = (_Float16)cond[((size_t)(b * 4 + ci) << 12) + p];
        }
        _Float16* dst = xh + ((size_t)i << 4);
#pragma unroll
        for (int q = 0; q < 2; ++q) *(f32x4*)(dst + q * 8) = *(f32x4*)(v + q * 8);
    }
}

// ---------------------------------------------------------------------------
// FUSED conv1+conv2 v3 (dense tap-pairing): conv1 runs 5 K=32-dense steps
// (tap pairs (0,1)(2,3)(4,5)(6,7) + tap 8 padded) instead of 9 half-zero
// steps: MFMA 144->80, w1l 72KB->40KB, bf reads halved. B-fragment k-split:
// quads 0-1 supply tap t0's pixel (k 0..15), quads 2-3 tap t1's (k 16..31)
// — per-lane address select on the SAME verified 16x16x32 layout.
// w1l+w2l now co-resident up front (40,960+32,768+512 = 74,240 B peak,
// unchanged -> 2 blocks/CU); h1l (34,816) overlays dead w1l after phase 1.
// ---------------------------------------------------------------------------
__global__ __launch_bounds__(256, 2) void conv12_k(
    const _Float16* __restrict__ xh, const _Float16* __restrict__ w1p,
    const _Float16* __restrict__ w2h, const float* __restrict__ b1,
    const float* __restrict__ b2, _Float16* __restrict__ h2p)
{
    __shared__ __align__(16) char smem[74240];
    // w1l [0,40960) | w2l [40960,73728) | b2l [73728,74240)
    // h1l overlay [0,34816) after phase 1
    float* b2l = (float*)(smem + 73728);
    _Float16* h1l = (_Float16*)smem;

    const int tid = threadIdx.x;
    const int wv = tid >> 6, lane = tid & 63;
    const int row16 = lane & 15, quad = lane >> 4;
    const int prow = wv >> 1, colb = (wv & 1) << 5;  // wv*32 = prow*64 + colb
    const int bid = blockIdx.x;            // 0..1023
    const int b = bid >> 5;
    const int pim0 = (bid & 31) << 7;      // 128-pixel tile
    const int h0 = pim0 >> 6;              // base image row (2 rows per tile)

    if (tid < 128) b2l[tid] = b2[tid];
#pragma unroll
    for (int k = 0; k < 10; ++k)                   // w1l: 2560 16B chunks
        ASYNC16(w1p + (size_t)(k * 256 + tid) * 8, smem + (k * 256 + wv * 64) * 16);
#pragma unroll
    for (int k = 0; k < 8; ++k)                    // w2l: 2048 16B chunks
        ASYNC16(w2h + (size_t)(k * 256 + tid) * 8, smem + 40960 + (k * 256 + wv * 64) * 16);

    f32x4 acc[2][8];
#pragma unroll
    for (int pt = 0; pt < 2; ++pt)
#pragma unroll
        for (int ot = 0; ot < 8; ++ot) acc[pt][ot] = (f32x4){0.f, 0.f, 0.f, 0.f};

    __syncthreads();                               // all staging drained
    const _Float16* wl = (const _Float16*)smem;

    // ---- phase 1: conv1 K-loop, 5 dense pair-steps (no inner barriers) ----
#pragma unroll
    for (int s = 0; s < 5; ++s) {
        const int t0 = 2 * s;
        const int t1 = (s < 4) ? 2 * s + 1 : 2 * s;          // s=4: dummy (wt=0)
        const int dy0 = t0 / 3, dx0 = t0 % 3;
        const int dy1 = t1 / 3, dx1 = t1 % 3;
        const int pb0 = (h0 + prow + dy0) * 66 + dx0 + colb + row16;
        const int pb1 = (h0 + prow + dy1) * 66 + dx1 + colb + row16;
        const int pbq = (quad < 2) ? pb0 : pb1;              // quads 0-1: t0; 2-3: t1
        const int koff = (quad & 1) * 8;                     // k-half within tap
        half8 bf[2], af[8];
#pragma unroll
        for (int pt = 0; pt < 2; ++pt)
            bf[pt] = *(const half8*)(xh + XH_IDX(b, pbq + pt * 16) + koff);
#pragma unroll
        for (int ot = 0; ot < 8; ++ot)
            af[ot] = *(const half8*)(wl + ((s * 128 + ot * 16 + row16) << 5) + quad * 8);
        __builtin_amdgcn_s_setprio(1);
#pragma unroll
        for (int ot = 0; ot < 8; ++ot)
#pragma unroll
            for (int pt = 0; pt < 2; ++pt)
                acc[pt][ot] = __builtin_amdgcn_mfma_f32_16x16x32_f16(af[ot], bf[pt], acc[pt][ot], 0, 0, 0);
        __builtin_amdgcn_s_setprio(0);
    }

    f32x4 bias[8];
#pragma unroll
    for (int ot = 0; ot < 8; ++ot) bias[ot] = *(const f32x4*)(b1 + ot * 16 + quad * 4);
    __syncthreads();                               // all w1l reads complete

    // ---- phase 2: ReLU(h1+b1) -> LDS tile (overlays dead w1l) ----
#pragma unroll
    for (int pt = 0; pt < 2; ++pt) {
        const int pix = wv * 32 + pt * 16 + row16;
#pragma unroll
        for (int ot = 0; ot < 8; ++ot) {
            half4 v;
#pragma unroll
            for (int r = 0; r < 4; ++r)
                v[r] = (_Float16)fmaxf(acc[pt][ot][r] + bias[ot][r], 0.f);
            *(half4*)(h1l + pix * 136 + ot * 16 + quad * 4) = v;
        }
    }
#pragma unroll
    for (int pt = 0; pt < 2; ++pt)
#pragma unroll
        for (int ot = 0; ot < 8; ++ot) acc[pt][ot] = (f32x4){0.f, 0.f, 0.f, 0.f};
    __syncthreads();                               // h1l visible to all waves

    // ---- phase 3: conv2 K-loop (both operands LDS, no inner barriers) ----
    const _Float16* w2l = (const _Float16*)(smem + 40960);
#pragma unroll
    for (int ks = 0; ks < 4; ++ks) {
        half8 bf[2], af[8];
#pragma unroll
        for (int pt = 0; pt < 2; ++pt)
            bf[pt] = *(const half8*)(h1l + (wv * 32 + pt * 16 + row16) * 136 + ks * 32 + quad * 8);
#pragma unroll
        for (int ot = 0; ot < 8; ++ot)
            af[ot] = *(const half8*)(w2l + ((ks * 128 + ot * 16 + row16) << 5) + quad * 8);
        __builtin_amdgcn_s_setprio(1);
#pragma unroll
        for (int ot = 0; ot < 8; ++ot)
#pragma unroll
            for (int pt = 0; pt < 2; ++pt)
                acc[pt][ot] = __builtin_amdgcn_mfma_f32_16x16x32_f16(af[ot], bf[pt], acc[pt][ot], 0, 0, 0);
        __builtin_amdgcn_s_setprio(0);
    }

    // ---- epilogue: ReLU(h2+b2) -> h2p interior ----
#pragma unroll
    for (int pt = 0; pt < 2; ++pt) {
        const int p = pim0 + wv * 32 + pt * 16 + row16;      // within-image pixel
        const int pp = ((p >> 6) + 1) * 66 + (p & 63) + 1;
#pragma unroll
        for (int ot = 0; ot < 8; ++ot) {
            const int oc0 = ot * 16 + quad * 4;
            half4 v;
#pragma unroll
            for (int r = 0; r < 4; ++r)
                v[r] = (_Float16)fmaxf(acc[pt][ot][r] + b2l[oc0 + r], 0.f);
            *(half4*)(h2p + H2P_IDX(b, oc0 >> 5, pp) + (oc0 & 31)) = v;
        }
    }
}

// ---------------------------------------------------------------------------
// RQS spline evaluation: params arrive as 6 x f32x4 (bias already added).
// Fast-math scope: hw-native exp/log + one reciprocal-squared fold
// (lad = log(dnum/denom^2) as a single log); softmax/div elsewhere exact.
// ---------------------------------------------------------------------------
__device__ __forceinline__ void rqs_eval(const f32x4* pv, float xv,
                                         float& yv_out, float& lad_out)
{
#define PRM(j) (pv[(j) >> 2][(j) & 3])
    const float xin = fminf(fmaxf(xv, -3.f), 3.f);

    float mw = PRM(0), mh = PRM(8);
#pragma unroll
    for (int j = 1; j < 8; ++j) { mw = fmaxf(mw, PRM(j)); mh = fmaxf(mh, PRM(8 + j)); }
    float ew[8], eh[8];
    float sw = 0.f, sh = 0.f;
#pragma unroll
    for (int j = 0; j < 8; ++j) {
        ew[j] = __expf(PRM(j) - mw);      sw += ew[j];
        eh[j] = __expf(PRM(8 + j) - mh);  sh += eh[j];
    }
    const float rw = 1.f / sw, rh = 1.f / sh;

    const float CONST_D = 0.5397423f;    // log(exp(1-MD)-1), MD=0.001

    float cumw = 0.f, cumh = 0.f;
    float cw_lo = -3.f, ch_lo = -3.f;
    float in_cw = 0.f, in_w = 1.f, in_ch = 0.f, in_h = 1.f, sd0 = 0.f, sd1 = 0.f;
#pragma unroll
    for (int i = 0; i < 8; ++i) {
        cumw += fmaf(0.992f, ew[i] * rw, 0.001f);
        cumh += fmaf(0.992f, eh[i] * rh, 0.001f);
        const float cw_hi = (i == 7) ? 3.f : fmaf(6.f, cumw, -3.f);
        const float ch_hi = (i == 7) ? 3.f : fmaf(6.f, cumh, -3.f);
        const bool sel = (xin >= cw_lo) && ((i == 7) || (xin < cw_hi));
        in_cw = sel ? cw_lo : in_cw;
        in_w  = sel ? (cw_hi - cw_lo) : in_w;
        in_ch = sel ? ch_lo : in_ch;
        in_h  = sel ? (ch_hi - ch_lo) : in_h;
        sd0   = sel ? ((i == 0) ? CONST_D : PRM(16 + i - 1)) : sd0;
        sd1   = sel ? ((i == 7) ? CONST_D : PRM(16 + i)) : sd1;
        cw_lo = cw_hi; ch_lo = ch_hi;
    }

    const float d0 = 0.001f + ((sd0 > 20.f) ? sd0 : __logf(1.f + __expf(sd0)));
    const float d1 = 0.001f + ((sd1 > 20.f) ? sd1 : __logf(1.f + __expf(sd1)));

    const float r_inw = 1.f / in_w;
    const float delta = in_h * r_inw;
    const float theta = (xin - in_cw) * r_inw;
    const float omt = 1.f - theta;
    const float tom = theta * omt;
    const float th2 = theta * theta;
    const float numer = in_h * (delta * th2 + d0 * tom);
    const float denom = delta + (d0 + d1 - 2.f * delta) * tom;
    const float rden = 1.f / denom;
    float yv = in_ch + numer * rden;
    const float dnum = delta * delta * (d1 * th2 + 2.f * delta * tom + d0 * omt * omt);
    float lad = __logf(dnum * rden * rden);

    const bool inside = (xv >= -3.f) && (xv <= 3.f);
    yv_out = inside ? yv : xv;
    lad_out = inside ? lad : 0.f;
#undef PRM
}

// ---------------------------------------------------------------------------
// conv3 v15 (unchanged from round 18 — best measured): v14 K-loop; epilogue
// lane-packed (2 pt-slices/phase -> 6 full 64-lane passes, 4 fences).
// 16x16x32, 12 row-steps, N=144, acc[4][9], launch_bounds(256,2),
// LDS 81,216 B, 2 blocks/CU. Grid 1024 = 64 groups x {2 cols x 8 ptiles}.
// Design-space closure (r3-r14) documented in session journal.
// ---------------------------------------------------------------------------
__global__ __launch_bounds__(256, 2) void conv3_rqs_k(
    const _Float16* __restrict__ h2p, const _Float16* __restrict__ w3h,
    const float* __restrict__ b3, const float* __restrict__ x,
    float* __restrict__ y, float* __restrict__ ld_out)
{
    __shared__ __align__(16) char smem[81216];
    // act [0,25344)  wt0 [25344,52992)  wt1 [52992,80640)  b3l [80640,81216)
    // epilogue overlay: epi 4 waves x 4736 floats = [0,75776)
    float* b3l = (float*)(smem + 80640);

    const int tid = threadIdx.x;
    const int wv = tid >> 6, lane = tid & 63;
    const int row16 = lane & 15, quad = lane >> 4;
    const int bid = blockIdx.x;            // 0..1023
    const int g = bid >> 4, r = bid & 15;  // XCD swizzle: 2 cols of a ptile
    const int col = r >> 3;                // 0..1 share bid%8 (same XCD)
    const int ptile = (g << 3) | (r & 7);  // 0..511
    const int b = ptile >> 4;
    const int pim0 = (ptile & 15) << 8;
    const int h0 = pim0 >> 6;              // base row, multiple of 4

    if (tid < 144) {
        const int c = tid / 24, j = tid % 24;
        b3l[tid] = (j < 23) ? b3[(col * 6 + c) * 23 + j] : 0.f;
    }

    f32x4 acc[4][9];
#pragma unroll
    for (int pt = 0; pt < 4; ++pt)
#pragma unroll
        for (int ot = 0; ot < 9; ++ot) acc[pt][ot] = (f32x4){0.f, 0.f, 0.f, 0.f};

    // ---- staging helpers (contiguous global->LDS via global_load_lds) ----
    auto stage_wt3 = [&](int dy, int cc, int buf) {
#pragma unroll
        for (int j = 0; j < 3; ++j) {
            const int t = dy * 3 + j;
            const _Float16* gp = w3h + ((size_t)((t * 4 + cc) * 288 + col * 144) << 5);
            char* wb = smem + 25344 + buf * 27648 + j * 9216;   // 576 chunks
            ASYNC16(gp + (size_t)tid * 8, wb + wv * 64 * 16);
            ASYNC16(gp + (size_t)(256 + tid) * 8, wb + (256 + wv * 64) * 16);
            if (wv == 0) ASYNC16(gp + (size_t)(512 + lane) * 8, wb + 512 * 16);
        }
    };
    auto stage_act = [&](int cc) {
        const _Float16* ga = h2p + H2P_IDX(b, cc, h0 * 66);   // 25344 B contiguous
#pragma unroll
        for (int k = 0; k < 6; ++k)
            ASYNC16(ga + (size_t)(k * 256 + tid) * 8, smem + (k * 256 + wv * 64) * 16);
        if (wv == 0 && lane < 48)
            ASYNC16(ga + (size_t)(1536 + lane) * 8, smem + 1536 * 16);
    };

    stage_act(0);
    stage_wt3(0, 0, 0);

    for (int cc = 0; cc < 4; ++cc) {
        for (int dy = 0; dy < 3; ++dy) {
            const int step = cc * 3 + dy;
            __syncthreads();               // staged data ready; other wt buf free
            if (step + 1 < 12)
                stage_wt3((dy == 2) ? 0 : dy + 1, (dy == 2) ? cc + 1 : cc, (step + 1) & 1);
            const _Float16* act = (const _Float16*)smem;
            const _Float16* wt = (const _Float16*)(smem + 25344 + (step & 1) * 27648);
            const int lrow = (wv + dy) * 66 + row16;
#pragma unroll
            for (int dx = 0; dx < 3; ++dx) {
                half8 bf[4], af[9];
#pragma unroll
                for (int pt = 0; pt < 4; ++pt)
                    bf[pt] = *(const half8*)(act + ((lrow + dx + pt * 16) << 5) + quad * 8);
#pragma unroll
                for (int ot = 0; ot < 9; ++ot)
                    af[ot] = *(const half8*)(wt + dx * 4608 + ((ot * 16 + row16) << 5) + quad * 8);
#pragma unroll
                for (int ot = 0; ot < 9; ++ot)
#pragma unroll
                    for (int pt = 0; pt < 4; ++pt)
                        acc[pt][ot] = __builtin_amdgcn_mfma_f32_16x16x32_f16(af[ot], bf[pt], acc[pt][ot], 0, 0, 0);
            }
            if (dy == 2 && cc < 3) {
                __syncthreads();           // act buffer dead for all waves
                stage_act(cc + 1);
            }
        }
    }
    __syncthreads();   // K-loop LDS reads done (all waves); epi overlay safe

    // ---- epilogue: wave-private epi slice; 2 pt-slices per phase ----
    float* epi = (float*)smem + wv * 4736;     // 2 x (16 pix x 148 floats)
    float lad_acc = 0.f;
#pragma unroll
    for (int ph = 0; ph < 2; ++ph) {           // pt pairs {0,1}, {2,3}
#pragma unroll
        for (int ptq = 0; ptq < 2; ++ptq)
#pragma unroll
            for (int ot = 0; ot < 9; ++ot)
                *(f32x4*)(epi + ptq * 2368 + row16 * 148 + ot * 16 + quad * 4)
                    = acc[ph * 2 + ptq][ot];
        // own-wave ds_writes complete before the dependent ds_reads below
        asm volatile("s_waitcnt lgkmcnt(0)" ::: "memory");
        __builtin_amdgcn_sched_barrier(0);     // rule #18: pin ops after the wait
#pragma unroll 1
        for (int pass = 0; pass < 3; ++pass) {
            const int idx = pass * 64 + lane;          // 0..191, all lanes live
            const int ptq = (idx >= 96) ? 1 : 0;
            const int rem = idx - ptq * 96;
            const int p16 = rem & 15, c = rem >> 4;    // c 0..5
            const float* pb = epi + ptq * 2368 + p16 * 148 + c * 24;
            const float* bb = b3l + c * 24;
            f32x4 pv[6];
#pragma unroll
            for (int q = 0; q < 6; ++q)
                pv[q] = *(const f32x4*)(pb + q * 4) + *(const f32x4*)(bb + q * 4);
            const int tpix = wv * 64 + (ph * 2 + ptq) * 16 + p16;
            const size_t xi = (((size_t)(b * 12 + col * 6 + c)) << 12) + (pim0 + tpix);
            const float xv = x[xi];
            float yv, lad;
            rqs_eval(pv, xv, yv, lad);
            y[xi] = yv;
            lad_acc += lad;
        }
        // reads of this phase complete before next phase's writes reuse epi
        asm volatile("s_waitcnt lgkmcnt(0)" ::: "memory");
        __builtin_amdgcn_sched_barrier(0);
    }

#pragma unroll
    for (int off = 32; off > 0; off >>= 1) lad_acc += __shfl_down(lad_acc, off);
    if (lane == 0) atomicAdd(&ld_out[b], lad_acc);
}

// ---------------------------------------------------------------------------
extern "C" void kernel_launch(void* const* d_in, const int* in_sizes, int n_in,
                              void* d_out, int out_size, void* d_ws, size_t ws_size,
                              hipStream_t stream)
{
    const float* x      = (const float*)d_in[0];
    const float* logdet = (const float*)d_in[1];
    const float* cond   = (const float*)d_in[2];
    const float* w1     = (const float*)d_in[3];
    const float* b1     = (const float*)d_in[4];
    const float* w2     = (const float*)d_in[5];
    const float* b2     = (const float*)d_in[6];
    const float* w3     = (const float*)d_in[7];
    const float* b3     = (const float*)d_in[8];

    char* ws = (char*)d_ws;
    _Float16* xh  = (_Float16*)ws;                       // 4,460,544 B (dense 16ch)
    _Float16* h2p = (_Float16*)(ws + 33554432);          // 35,684,352 B
    _Float16* w1p = (_Float16*)(ws + 69238784);          // 40,960 B (tap-paired)
    _Float16* w2h = (_Float16*)(ws + 69312512);          // 32,768 B
    _Float16* w3h = (_Float16*)(ws + 69345280);          // 663,552 B (end ~70 MB)

    float* y      = (float*)d_out;                       // NY floats
    float* ld_out = y + NY;                              // 32 floats

    prep_xh_k<<<1296, 256, 0, stream>>>(w1, w2, w3, w1p, w2h, w3h, logdet, ld_out, x, cond, xh, h2p);
    conv12_k<<<1024, 256, 0, stream>>>(xh, w1p, w2h, b1, b2, h2p);
    conv3_rqs_k<<<1024, 256, 0, stream>>>(h2p, w3h, b3, x, y, ld_out);
}